// Round 2
// baseline (572.684 us; speedup 1.0000x reference)
//
#include <hip/hip_runtime.h>
#include <hip/hip_bf16.h>
#include <stdint.h>

#define BATCH 16384
#define FACE_K 64
#define VISUAL_DIM 2048
#define HIDDEN 512
#define NUM_USERS 1000000
#define NUM_AGES 8
#define NUM_ATTR 40
#define VOCAB (NUM_USERS + 24 + 2 + NUM_AGES + NUM_ATTR)
#define XDIM 384

typedef __bf16 bf16x8 __attribute__((ext_vector_type(8)));
typedef float f32x4 __attribute__((ext_vector_type(4)));

__device__ __forceinline__ uint16_t f2bf(float f) {
    union { float f; uint32_t u; } v; v.f = f;
    uint32_t r = v.u + 0x7fffu + ((v.u >> 16) & 1u);
    return (uint16_t)(r >> 16);
}
__device__ __forceinline__ float bf2f(uint16_t h) {
    union { uint32_t u; float f; } v; v.u = ((uint32_t)h) << 16;
    return v.f;
}

// ---------------- weight f32 -> bf16 cast ----------------
__global__ void cvt_f32_bf16(const float* __restrict__ src, uint16_t* __restrict__ dst, int n4) {
    int i = blockIdx.x * blockDim.x + threadIdx.x;
    if (i < n4) {
        float4 v = ((const float4*)src)[i];
        ushort4 o;
        o.x = f2bf(v.x); o.y = f2bf(v.y); o.z = f2bf(v.z); o.w = f2bf(v.w);
        ((ushort4*)dst)[i] = o;
    }
}

// ---------------- embeddings + FM (wave per row, lane = k) ----------------
__global__ void embed_fm_kernel(const int* __restrict__ uid, const int* __restrict__ hour,
                                const float* __restrict__ scale, const int* __restrict__ gender,
                                const int* __restrict__ age, const int* __restrict__ attr,
                                const float* __restrict__ user_emb, const float* __restrict__ hour_emb,
                                const float* __restrict__ gender_emb, const float* __restrict__ age_emb,
                                const float* __restrict__ attr_emb,
                                const float* __restrict__ fm_w, const float* __restrict__ fm_b,
                                uint16_t* __restrict__ x, float* __restrict__ fm) {
    int row = blockIdx.x * 4 + (threadIdx.x >> 6);
    int lane = threadIdx.x & 63;
    int u = uid[row], h = hour[row], g = gender[row], a = age[row], at = attr[row];
    float sc = scale[row];
    float eu  = user_emb[(size_t)u * 64 + lane];
    float eh  = hour_emb[h * 64 + lane];
    float eg  = sc * tanhf(gender_emb[g * 64 + lane]);
    float eat = sc * tanhf(attr_emb[at * 64 + lane]);
    float eag = sc * tanhf(age_emb[a * 64 + lane]);
    float s  = eu + eh + eg + eat + eag;
    float sq = eu*eu + eh*eh + eg*eg + eat*eat + eag*eag;
    float so = s * s - sq;
    float l0 = 0.f, l1 = 0.f;
    if (lane < 5) {
        int col = (lane == 0) ? u
                : (lane == 1) ? (NUM_USERS + h)
                : (lane == 2) ? (NUM_USERS + 24 + g)
                : (lane == 3) ? (NUM_USERS + 26 + a)
                :               (NUM_USERS + 34 + at);
        l0 = fm_w[col];
        l1 = fm_w[VOCAB + col];
    }
    for (int m = 32; m; m >>= 1) {
        so += __shfl_xor(so, m);
        l0 += __shfl_xor(l0, m);
        l1 += __shfl_xor(l1, m);
    }
    if (lane == 0) {
        fm[row * 2 + 0] = l0 + fm_b[0] + 0.5f * so;
        fm[row * 2 + 1] = l1 + fm_b[1] + 0.5f * so;
    }
    size_t xb = (size_t)row * XDIM;
    x[xb +       lane] = f2bf(eu);
    x[xb +  64 + lane] = f2bf(eh);
    x[xb + 128 + lane] = f2bf(eg);
    x[xb + 192 + lane] = f2bf(eat);
    x[xb + 256 + lane] = f2bf(eag);
}

// ---------------- visual GEMM: LDS-free, direct MFMA fragment loads ----------------
// block = 128 thr (2 waves), each block: 16 rows x 64 cols; waves split K (1024 each)
__global__ __launch_bounds__(128) void visual_gemm(const float* __restrict__ visual,
                                                   const uint16_t* __restrict__ Wb,
                                                   const float* __restrict__ bias,
                                                   uint16_t* __restrict__ x) {
    __shared__ float red[64 * 16];
    int wv = threadIdx.x >> 6, lane = threadIdx.x & 63;
    int lc = lane & 15, quad = lane >> 4;
    int m0 = blockIdx.x * 16;

    const float*    ap = visual + (size_t)(m0 + lc) * VISUAL_DIM + quad * 8 + wv * 1024;
    const uint16_t* wp = Wb + (size_t)lc * VISUAL_DIM + quad * 8 + wv * 1024;

    f32x4 acc[4];
    #pragma unroll
    for (int j = 0; j < 4; ++j) acc[j] = (f32x4){0.f, 0.f, 0.f, 0.f};

    #pragma unroll 2
    for (int k = 0; k < 1024; k += 32) {
        float4 a0 = *(const float4*)(ap + k);
        float4 a1 = *(const float4*)(ap + k + 4);
        bf16x8 af;
        af[0] = (__bf16)a0.x; af[1] = (__bf16)a0.y; af[2] = (__bf16)a0.z; af[3] = (__bf16)a0.w;
        af[4] = (__bf16)a1.x; af[5] = (__bf16)a1.y; af[6] = (__bf16)a1.z; af[7] = (__bf16)a1.w;
        #pragma unroll
        for (int j = 0; j < 4; ++j) {
            bf16x8 bf = *(const bf16x8*)(wp + (size_t)(j * 16) * VISUAL_DIM + k);
            acc[j] = __builtin_amdgcn_mfma_f32_16x16x32_bf16(af, bf, acc[j], 0, 0, 0);
        }
    }
    if (wv == 1) {
        #pragma unroll
        for (int j = 0; j < 4; ++j)
            *(f32x4*)(&red[lane * 16 + j * 4]) = acc[j];
    }
    __syncthreads();
    if (wv == 0) {
        #pragma unroll
        for (int j = 0; j < 4; ++j) {
            f32x4 o = *(const f32x4*)(&red[lane * 16 + j * 4]);
            int col = j * 16 + lc;
            float b = bias[col];
            #pragma unroll
            for (int r = 0; r < 4; ++r) {
                int row = m0 + quad * 4 + r;
                x[(size_t)row * XDIM + 320 + col] = f2bf(acc[j][r] + o[r] + b);
            }
        }
    }
}

// ---------------- layer GEMM: LDS-free, direct MFMA fragment loads ----------------
// block = 256 (4 waves); wave = 16 rows x 64 cols; grid (M/64, N/64)
template <int KTOT, bool RELU>
__global__ __launch_bounds__(256) void gemm_direct(const uint16_t* __restrict__ A,
                                                   const uint16_t* __restrict__ W,
                                                   const float* __restrict__ bias,
                                                   uint16_t* __restrict__ C, int ldc) {
    int wv = threadIdx.x >> 6, lane = threadIdx.x & 63;
    int lc = lane & 15, quad = lane >> 4;
    int m0 = blockIdx.x * 64 + wv * 16;
    int n0 = blockIdx.y * 64;

    const uint16_t* ap = A + (size_t)(m0 + lc) * KTOT + quad * 8;
    const uint16_t* wp = W + (size_t)(n0 + lc) * KTOT + quad * 8;

    f32x4 acc[4];
    #pragma unroll
    for (int j = 0; j < 4; ++j) acc[j] = (f32x4){0.f, 0.f, 0.f, 0.f};

    #pragma unroll 2
    for (int k = 0; k < KTOT; k += 32) {
        bf16x8 af = *(const bf16x8*)(ap + k);
        #pragma unroll
        for (int j = 0; j < 4; ++j) {
            bf16x8 bf = *(const bf16x8*)(wp + (size_t)(j * 16) * KTOT + k);
            acc[j] = __builtin_amdgcn_mfma_f32_16x16x32_bf16(af, bf, acc[j], 0, 0, 0);
        }
    }
    #pragma unroll
    for (int j = 0; j < 4; ++j) {
        int col = n0 + j * 16 + lc;
        float b = bias[col];
        #pragma unroll
        for (int r = 0; r < 4; ++r) {
            int row = m0 + quad * 4 + r;
            float v = acc[j][r] + b;
            if (RELU) v = fmaxf(v, 0.f);
            C[(size_t)row * ldc + col] = f2bf(v);
        }
    }
}

// ---------------- final: h2 @ w3^T + fm + b3 -> softmax ----------------
__global__ void final_kernel(const uint16_t* __restrict__ h2, const float* __restrict__ w3,
                             const float* __restrict__ b3, const float* __restrict__ fm,
                             float* __restrict__ out) {
    int row = blockIdx.x * 4 + (threadIdx.x >> 6);
    int lane = threadIdx.x & 63;
    uint4 hv = *(const uint4*)(h2 + (size_t)row * HIDDEN + lane * 8);
    const uint16_t* hp = (const uint16_t*)&hv;
    float4 wa0 = *(const float4*)(w3 + lane * 8);
    float4 wb0 = *(const float4*)(w3 + lane * 8 + 4);
    float4 wa1 = *(const float4*)(w3 + HIDDEN + lane * 8);
    float4 wb1 = *(const float4*)(w3 + HIDDEN + lane * 8 + 4);
    float hf[8];
    #pragma unroll
    for (int j = 0; j < 8; ++j) hf[j] = bf2f(hp[j]);
    float d0 = hf[0]*wa0.x + hf[1]*wa0.y + hf[2]*wa0.z + hf[3]*wa0.w
             + hf[4]*wb0.x + hf[5]*wb0.y + hf[6]*wb0.z + hf[7]*wb0.w;
    float d1 = hf[0]*wa1.x + hf[1]*wa1.y + hf[2]*wa1.z + hf[3]*wa1.w
             + hf[4]*wb1.x + hf[5]*wb1.y + hf[6]*wb1.z + hf[7]*wb1.w;
    for (int m = 32; m; m >>= 1) {
        d0 += __shfl_xor(d0, m);
        d1 += __shfl_xor(d1, m);
    }
    if (lane == 0) {
        float l0 = fm[row * 2 + 0] + d0 + b3[0];
        float l1 = fm[row * 2 + 1] + d1 + b3[1];
        float mx = fmaxf(l0, l1);
        float e0 = __expf(l0 - mx), e1 = __expf(l1 - mx);
        float inv = 1.f / (e0 + e1);
        out[row * 2 + 0] = e0 * inv;
        out[row * 2 + 1] = e1 * inv;
    }
}

extern "C" void kernel_launch(void* const* d_in, const int* in_sizes, int n_in,
                              void* d_out, int out_size, void* d_ws, size_t ws_size,
                              hipStream_t stream) {
    const int*   user_id   = (const int*)d_in[0];
    const int*   hour      = (const int*)d_in[1];
    const float* visual    = (const float*)d_in[2];
    const float* scale     = (const float*)d_in[3];
    const int*   gender    = (const int*)d_in[4];
    const int*   age       = (const int*)d_in[5];
    const int*   attribute = (const int*)d_in[6];
    const float* user_emb  = (const float*)d_in[7];
    const float* hour_emb  = (const float*)d_in[8];
    const float* gender_emb= (const float*)d_in[9];
    const float* age_emb   = (const float*)d_in[10];
    const float* attr_emb  = (const float*)d_in[11];
    const float* visu_w    = (const float*)d_in[12];
    const float* visu_b    = (const float*)d_in[13];
    const float* fm_w      = (const float*)d_in[14];
    const float* fm_b      = (const float*)d_in[15];
    const float* w1        = (const float*)d_in[16];
    const float* b1        = (const float*)d_in[17];
    const float* w2        = (const float*)d_in[18];
    const float* b2        = (const float*)d_in[19];
    const float* w3        = (const float*)d_in[20];
    const float* b3        = (const float*)d_in[21];
    float* out = (float*)d_out;

    char* ws = (char*)d_ws;
    uint16_t* x   = (uint16_t*)ws;                                        // 16384*384*2
    uint16_t* h1  = (uint16_t*)(ws + 12582912);                           // 16384*512*2
    uint16_t* h2  = (uint16_t*)(ws + 12582912 + 16777216);                // 16384*512*2
    float*    fm  = (float*)   (ws + 12582912 + 2 * 16777216);            // 16384*2*4
    uint16_t* vwb = (uint16_t*)(ws + 12582912 + 2 * 16777216 + 131072);   // 64*2048*2
    uint16_t* w1b = vwb + 64 * 2048;                                      // 512*384*2
    uint16_t* w2b = w1b + 512 * 384;                                      // 512*512*2

    // weight casts
    {
        int n4 = 64 * 2048 / 4;
        cvt_f32_bf16<<<(n4 + 255) / 256, 256, 0, stream>>>(visu_w, vwb, n4);
        n4 = 512 * 384 / 4;
        cvt_f32_bf16<<<(n4 + 255) / 256, 256, 0, stream>>>(w1, w1b, n4);
        n4 = 512 * 512 / 4;
        cvt_f32_bf16<<<(n4 + 255) / 256, 256, 0, stream>>>(w2, w2b, n4);
    }
    // embeddings + FM
    embed_fm_kernel<<<BATCH / 4, 256, 0, stream>>>(user_id, hour, scale, gender, age, attribute,
                                                   user_emb, hour_emb, gender_emb, age_emb,
                                                   attr_emb, fm_w, fm_b, x, fm);
    // visual projection into x[:,320:384]
    visual_gemm<<<BATCH / 16, 128, 0, stream>>>(visual, vwb, visu_b, x);
    // DNN layers
    gemm_direct<XDIM, true><<<dim3(BATCH / 64, 8), 256, 0, stream>>>(x, w1b, b1, h1, HIDDEN);
    gemm_direct<HIDDEN, true><<<dim3(BATCH / 64, 8), 256, 0, stream>>>(h1, w2b, b2, h2, HIDDEN);
    // final layer + FM combine + softmax
    final_kernel<<<BATCH / 4, 256, 0, stream>>>(h2, w3, b3, fm, out);
}

// Round 3
// 514.115 us; speedup vs baseline: 1.1139x; 1.1139x over previous
//
#include <hip/hip_runtime.h>
#include <hip/hip_bf16.h>
#include <stdint.h>

#define BATCH 16384
#define FACE_K 64
#define VISUAL_DIM 2048
#define HIDDEN 512
#define NUM_USERS 1000000
#define NUM_AGES 8
#define NUM_ATTR 40
#define VOCAB (NUM_USERS + 24 + 2 + NUM_AGES + NUM_ATTR)
#define XDIM 384

typedef __bf16 bf16x8 __attribute__((ext_vector_type(8)));
typedef float f32x4 __attribute__((ext_vector_type(4)));

__device__ __forceinline__ uint16_t f2bf(float f) {
    union { float f; uint32_t u; } v; v.f = f;
    uint32_t r = v.u + 0x7fffu + ((v.u >> 16) & 1u);
    return (uint16_t)(r >> 16);
}
__device__ __forceinline__ float bf2f(uint16_t h) {
    union { uint32_t u; float f; } v; v.u = ((uint32_t)h) << 16;
    return v.f;
}

// ---------------- fused weight casts: visu_w | w1 | w2 in one launch ----------------
// float4 counts: visu 32768, w1 49152, w2 65536  (total 147456 = 576 blocks x 256)
__global__ void cvt_all(const float* __restrict__ visu_w, const float* __restrict__ w1,
                        const float* __restrict__ w2, uint16_t* __restrict__ vwb,
                        uint16_t* __restrict__ w1b, uint16_t* __restrict__ w2b) {
    int i = blockIdx.x * blockDim.x + threadIdx.x;
    const float4* src;
    ushort4* dst;
    if (i < 32768)       { src = (const float4*)visu_w + i;        dst = (ushort4*)vwb + i; }
    else if (i < 81920)  { src = (const float4*)w1 + (i - 32768);  dst = (ushort4*)w1b + (i - 32768); }
    else                 { src = (const float4*)w2 + (i - 81920);  dst = (ushort4*)w2b + (i - 81920); }
    float4 v = *src;
    ushort4 o;
    o.x = f2bf(v.x); o.y = f2bf(v.y); o.z = f2bf(v.z); o.w = f2bf(v.w);
    *dst = o;
}

// ---------------- front kernel: visual GEMM (blocks 0..1023) + embed/FM (1024..5119) ----
// visual: block = 16 rows x 64 cols, 4 waves split K (512 each); reduce via LDS
#define VIS_BLOCKS 1024
__global__ __launch_bounds__(256) void front_kernel(
        const float* __restrict__ visual, const uint16_t* __restrict__ Wb,
        const float* __restrict__ bias,
        const int* __restrict__ uid, const int* __restrict__ hour,
        const float* __restrict__ scale, const int* __restrict__ gender,
        const int* __restrict__ age, const int* __restrict__ attr,
        const float* __restrict__ user_emb, const float* __restrict__ hour_emb,
        const float* __restrict__ gender_emb, const float* __restrict__ age_emb,
        const float* __restrict__ attr_emb,
        const float* __restrict__ fm_w, const float* __restrict__ fm_b,
        uint16_t* __restrict__ x, float* __restrict__ fm) {
    __shared__ float red[3 * 64 * 17];
    int t = threadIdx.x;
    int wv = t >> 6, lane = t & 63;

    if (blockIdx.x < VIS_BLOCKS) {
        // ---- visual GEMM tile ----
        int lc = lane & 15, quad = lane >> 4;
        int m0 = blockIdx.x * 16;
        const float*    ap = visual + (size_t)(m0 + lc) * VISUAL_DIM + wv * 512 + quad * 8;
        const uint16_t* wp = Wb + (size_t)lc * VISUAL_DIM + wv * 512 + quad * 8;

        f32x4 acc[4];
        #pragma unroll
        for (int j = 0; j < 4; ++j) acc[j] = (f32x4){0.f, 0.f, 0.f, 0.f};

        #pragma unroll 4
        for (int k = 0; k < 512; k += 32) {
            float4 a0 = *(const float4*)(ap + k);
            float4 a1 = *(const float4*)(ap + k + 4);
            bf16x8 af;
            af[0] = (__bf16)a0.x; af[1] = (__bf16)a0.y; af[2] = (__bf16)a0.z; af[3] = (__bf16)a0.w;
            af[4] = (__bf16)a1.x; af[5] = (__bf16)a1.y; af[6] = (__bf16)a1.z; af[7] = (__bf16)a1.w;
            #pragma unroll
            for (int j = 0; j < 4; ++j) {
                bf16x8 bf = *(const bf16x8*)(wp + (size_t)(j * 16) * VISUAL_DIM + k);
                acc[j] = __builtin_amdgcn_mfma_f32_16x16x32_bf16(af, bf, acc[j], 0, 0, 0);
            }
        }
        if (wv) {
            int base = (wv - 1) * 1088 + lane * 17;
            #pragma unroll
            for (int j = 0; j < 4; ++j)
                #pragma unroll
                for (int r = 0; r < 4; ++r)
                    red[base + j * 4 + r] = acc[j][r];
        }
        __syncthreads();
        if (wv == 0) {
            int base = lane * 17;
            #pragma unroll
            for (int j = 0; j < 4; ++j) {
                int col = j * 16 + lc;
                float b = bias[col];
                #pragma unroll
                for (int r = 0; r < 4; ++r) {
                    float sum = acc[j][r] + red[base + j * 4 + r]
                              + red[1088 + base + j * 4 + r] + red[2176 + base + j * 4 + r];
                    int row = m0 + quad * 4 + r;
                    x[(size_t)row * XDIM + 320 + col] = f2bf(sum + b);
                }
            }
        }
    } else {
        // ---- embeddings + FM, wave per row ----
        int row = (blockIdx.x - VIS_BLOCKS) * 4 + wv;
        int u = uid[row], h = hour[row], g = gender[row], a = age[row], at = attr[row];
        float sc = scale[row];
        float eu  = user_emb[(size_t)u * 64 + lane];
        float eh  = hour_emb[h * 64 + lane];
        float eg  = sc * tanhf(gender_emb[g * 64 + lane]);
        float eat = sc * tanhf(attr_emb[at * 64 + lane]);
        float eag = sc * tanhf(age_emb[a * 64 + lane]);
        float s  = eu + eh + eg + eat + eag;
        float sq = eu*eu + eh*eh + eg*eg + eat*eat + eag*eag;
        float so = s * s - sq;
        float l0 = 0.f, l1 = 0.f;
        if (lane < 5) {
            int col = (lane == 0) ? u
                    : (lane == 1) ? (NUM_USERS + h)
                    : (lane == 2) ? (NUM_USERS + 24 + g)
                    : (lane == 3) ? (NUM_USERS + 26 + a)
                    :               (NUM_USERS + 34 + at);
            l0 = fm_w[col];
            l1 = fm_w[VOCAB + col];
        }
        for (int m = 32; m; m >>= 1) {
            so += __shfl_xor(so, m);
            l0 += __shfl_xor(l0, m);
            l1 += __shfl_xor(l1, m);
        }
        if (lane == 0) {
            fm[row * 2 + 0] = l0 + fm_b[0] + 0.5f * so;
            fm[row * 2 + 1] = l1 + fm_b[1] + 0.5f * so;
        }
        size_t xb = (size_t)row * XDIM;
        x[xb +       lane] = f2bf(eu);
        x[xb +  64 + lane] = f2bf(eh);
        x[xb + 128 + lane] = f2bf(eg);
        x[xb + 192 + lane] = f2bf(eat);
        x[xb + 256 + lane] = f2bf(eag);
    }
}

// ---------------- layer GEMM: wave = 32 rows x 64 cols, direct fragment loads ----------
// grid (M/128, N/64), block 256 (4 waves)
template <int KTOT, bool RELU>
__global__ __launch_bounds__(256) void gemm32(const uint16_t* __restrict__ A,
                                              const uint16_t* __restrict__ W,
                                              const float* __restrict__ bias,
                                              uint16_t* __restrict__ C, int ldc) {
    int wv = threadIdx.x >> 6, lane = threadIdx.x & 63;
    int lc = lane & 15, quad = lane >> 4;
    int m0 = blockIdx.x * 128 + wv * 32;
    int n0 = blockIdx.y * 64;

    const uint16_t* ap0 = A + (size_t)(m0 + lc) * KTOT + quad * 8;
    const uint16_t* ap1 = ap0 + (size_t)16 * KTOT;
    const uint16_t* wp  = W + (size_t)(n0 + lc) * KTOT + quad * 8;

    f32x4 acc[2][4];
    #pragma unroll
    for (int i = 0; i < 2; ++i)
        #pragma unroll
        for (int j = 0; j < 4; ++j) acc[i][j] = (f32x4){0.f, 0.f, 0.f, 0.f};

    #pragma unroll 4
    for (int k = 0; k < KTOT; k += 32) {
        bf16x8 af0 = *(const bf16x8*)(ap0 + k);
        bf16x8 af1 = *(const bf16x8*)(ap1 + k);
        #pragma unroll
        for (int j = 0; j < 4; ++j) {
            bf16x8 bf = *(const bf16x8*)(wp + (size_t)(j * 16) * KTOT + k);
            acc[0][j] = __builtin_amdgcn_mfma_f32_16x16x32_bf16(af0, bf, acc[0][j], 0, 0, 0);
            acc[1][j] = __builtin_amdgcn_mfma_f32_16x16x32_bf16(af1, bf, acc[1][j], 0, 0, 0);
        }
    }
    #pragma unroll
    for (int j = 0; j < 4; ++j) {
        int col = n0 + j * 16 + lc;
        float b = bias[col];
        #pragma unroll
        for (int i = 0; i < 2; ++i) {
            #pragma unroll
            for (int r = 0; r < 4; ++r) {
                int row = m0 + i * 16 + quad * 4 + r;
                float v = acc[i][j][r] + b;
                if (RELU) v = fmaxf(v, 0.f);
                C[(size_t)row * ldc + col] = f2bf(v);
            }
        }
    }
}

// ---------------- final: h2 @ w3^T + fm + b3 -> softmax ----------------
__global__ void final_kernel(const uint16_t* __restrict__ h2, const float* __restrict__ w3,
                             const float* __restrict__ b3, const float* __restrict__ fm,
                             float* __restrict__ out) {
    int row = blockIdx.x * 4 + (threadIdx.x >> 6);
    int lane = threadIdx.x & 63;
    uint4 hv = *(const uint4*)(h2 + (size_t)row * HIDDEN + lane * 8);
    const uint16_t* hp = (const uint16_t*)&hv;
    float4 wa0 = *(const float4*)(w3 + lane * 8);
    float4 wb0 = *(const float4*)(w3 + lane * 8 + 4);
    float4 wa1 = *(const float4*)(w3 + HIDDEN + lane * 8);
    float4 wb1 = *(const float4*)(w3 + HIDDEN + lane * 8 + 4);
    float hf[8];
    #pragma unroll
    for (int j = 0; j < 8; ++j) hf[j] = bf2f(hp[j]);
    float d0 = hf[0]*wa0.x + hf[1]*wa0.y + hf[2]*wa0.z + hf[3]*wa0.w
             + hf[4]*wb0.x + hf[5]*wb0.y + hf[6]*wb0.z + hf[7]*wb0.w;
    float d1 = hf[0]*wa1.x + hf[1]*wa1.y + hf[2]*wa1.z + hf[3]*wa1.w
             + hf[4]*wb1.x + hf[5]*wb1.y + hf[6]*wb1.z + hf[7]*wb1.w;
    for (int m = 32; m; m >>= 1) {
        d0 += __shfl_xor(d0, m);
        d1 += __shfl_xor(d1, m);
    }
    if (lane == 0) {
        float l0 = fm[row * 2 + 0] + d0 + b3[0];
        float l1 = fm[row * 2 + 1] + d1 + b3[1];
        float mx = fmaxf(l0, l1);
        float e0 = __expf(l0 - mx), e1 = __expf(l1 - mx);
        float inv = 1.f / (e0 + e1);
        out[row * 2 + 0] = e0 * inv;
        out[row * 2 + 1] = e1 * inv;
    }
}

extern "C" void kernel_launch(void* const* d_in, const int* in_sizes, int n_in,
                              void* d_out, int out_size, void* d_ws, size_t ws_size,
                              hipStream_t stream) {
    const int*   user_id   = (const int*)d_in[0];
    const int*   hour      = (const int*)d_in[1];
    const float* visual    = (const float*)d_in[2];
    const float* scale     = (const float*)d_in[3];
    const int*   gender    = (const int*)d_in[4];
    const int*   age       = (const int*)d_in[5];
    const int*   attribute = (const int*)d_in[6];
    const float* user_emb  = (const float*)d_in[7];
    const float* hour_emb  = (const float*)d_in[8];
    const float* gender_emb= (const float*)d_in[9];
    const float* age_emb   = (const float*)d_in[10];
    const float* attr_emb  = (const float*)d_in[11];
    const float* visu_w    = (const float*)d_in[12];
    const float* visu_b    = (const float*)d_in[13];
    const float* fm_w      = (const float*)d_in[14];
    const float* fm_b      = (const float*)d_in[15];
    const float* w1        = (const float*)d_in[16];
    const float* b1        = (const float*)d_in[17];
    const float* w2        = (const float*)d_in[18];
    const float* b2        = (const float*)d_in[19];
    const float* w3        = (const float*)d_in[20];
    const float* b3        = (const float*)d_in[21];
    float* out = (float*)d_out;

    char* ws = (char*)d_ws;
    uint16_t* x   = (uint16_t*)ws;                                        // 16384*384*2
    uint16_t* h1  = (uint16_t*)(ws + 12582912);                           // 16384*512*2
    uint16_t* h2  = (uint16_t*)(ws + 12582912 + 16777216);                // 16384*512*2
    float*    fm  = (float*)   (ws + 12582912 + 2 * 16777216);            // 16384*2*4
    uint16_t* vwb = (uint16_t*)(ws + 12582912 + 2 * 16777216 + 131072);   // 64*2048*2
    uint16_t* w1b = vwb + 64 * 2048;                                      // 512*384*2
    uint16_t* w2b = w1b + 512 * 384;                                      // 512*512*2

    // all weight casts in one launch
    cvt_all<<<576, 256, 0, stream>>>(visu_w, w1, w2, vwb, w1b, w2b);
    // visual GEMM + embeddings/FM fused in one launch (disjoint block ranges)
    front_kernel<<<VIS_BLOCKS + BATCH / 4, 256, 0, stream>>>(
        visual, vwb, visu_b,
        user_id, hour, scale, gender, age, attribute,
        user_emb, hour_emb, gender_emb, age_emb, attr_emb,
        fm_w, fm_b, x, fm);
    // DNN layers
    gemm32<XDIM, true><<<dim3(BATCH / 128, 8), 256, 0, stream>>>(x, w1b, b1, h1, HIDDEN);
    gemm32<HIDDEN, true><<<dim3(BATCH / 128, 8), 256, 0, stream>>>(h1, w2b, b2, h2, HIDDEN);
    // final layer + FM combine + softmax
    final_kernel<<<BATCH / 4, 256, 0, stream>>>(h2, w3, b3, fm, out);
}